// Round 1
// baseline (211.781 us; speedup 1.0000x reference)
//
#include <hip/hip_runtime.h>

#define BB 8
#define TT 4096
#define CC 512
#define NCHUNK 128
#define LCHUNK (TT / NCHUNK)   // 32

// Pass 1: per-chunk local scan with zero initial state; store chunk-end state.
__global__ __launch_bounds__(256) void rec_pass1(const float* __restrict__ x,
                                                 const float* __restrict__ Ar,
                                                 const float* __restrict__ Ai,
                                                 float2* __restrict__ s_end) {
    const int tid   = threadIdx.x;            // handles channels 2*tid, 2*tid+1
    const int blk   = blockIdx.x;             // b * NCHUNK + chunk
    const int b     = blk / NCHUNK;
    const int chunk = blk % NCHUNK;
    const int t0    = chunk * LCHUNK;

    const float2 a_r = ((const float2*)Ar)[tid];
    const float2 a_i = ((const float2*)Ai)[tid];

    const float2* xp = (const float2*)(x + (size_t)(b * TT + t0) * CC) + tid;

    float hr0 = 0.f, hi0 = 0.f, hr1 = 0.f, hi1 = 0.f;
#pragma unroll 8
    for (int t = 0; t < LCHUNK; ++t) {
        float2 xv = xp[(size_t)t * (CC / 2)];
        float nr0 = fmaf(hr0, a_r.x, fmaf(-hi0, a_i.x, xv.x));
        float ni0 = fmaf(a_i.x, hr0, a_r.x * hi0);
        float nr1 = fmaf(hr1, a_r.y, fmaf(-hi1, a_i.y, xv.y));
        float ni1 = fmaf(a_i.y, hr1, a_r.y * hi1);
        hr0 = nr0; hi0 = ni0; hr1 = nr1; hi1 = ni1;
    }
    float4* sp = (float4*)(s_end + (size_t)(chunk * BB + b) * CC);
    sp[tid] = make_float4(hr0, hi0, hr1, hi1);
}

// Pass 2: sequential combine across chunks: h_start[j] = A^L * h_start[j-1] + s_end[j-1]
__global__ __launch_bounds__(256) void rec_pass2(const float* __restrict__ Ar,
                                                 const float* __restrict__ Ai,
                                                 const float* __restrict__ h0r,
                                                 const float* __restrict__ h0i,
                                                 const float2* __restrict__ s_end,
                                                 float2* __restrict__ h_start) {
    const int gid = blockIdx.x * 256 + threadIdx.x;   // 0 .. BB*CC-1
    const int b = gid / CC;
    const int c = gid % CC;

    float ar = Ar[c], ai = Ai[c];
    // A^LCHUNK via repeated squaring (LCHUNK = 32 = 2^5)
    float pr = ar, pi = ai;
#pragma unroll
    for (int s = 0; s < 5; ++s) {
        float nr = pr * pr - pi * pi;
        float ni = 2.f * pr * pi;
        pr = nr; pi = ni;
    }

    float hr = h0r[gid], hi = h0i[gid];   // gid == b*CC + c
#pragma unroll 4
    for (int j = 0; j < NCHUNK; ++j) {
        h_start[(size_t)(j * BB + b) * CC + c] = make_float2(hr, hi);
        float2 s = s_end[(size_t)(j * BB + b) * CC + c];
        float nr = pr * hr - pi * hi + s.x;
        float ni = pi * hr + pr * hi + s.y;
        hr = nr; hi = ni;
    }
}

// Pass 3: re-run each chunk from its correct start state and emit every step.
__global__ __launch_bounds__(256) void rec_pass3(const float* __restrict__ x,
                                                 const float* __restrict__ Ar,
                                                 const float* __restrict__ Ai,
                                                 const float2* __restrict__ h_start,
                                                 float4* __restrict__ out) {
    const int tid   = threadIdx.x;
    const int blk   = blockIdx.x;
    const int b     = blk / NCHUNK;
    const int chunk = blk % NCHUNK;
    const int t0    = chunk * LCHUNK;

    const float2 a_r = ((const float2*)Ar)[tid];
    const float2 a_i = ((const float2*)Ai)[tid];

    const float2* xp = (const float2*)(x + (size_t)(b * TT + t0) * CC) + tid;
    const float4* hs = (const float4*)(h_start + (size_t)(chunk * BB + b) * CC);
    float4 h = hs[tid];
    float hr0 = h.x, hi0 = h.y, hr1 = h.z, hi1 = h.w;

    // out is (B,T,C,2) floats; one float4 covers 2 channels (r,i,r,i)
    float4* op = out + (size_t)(b * TT + t0) * (CC / 2) + tid;  // CC*2/4 = CC/2 float4 per t-row
#pragma unroll 8
    for (int t = 0; t < LCHUNK; ++t) {
        float2 xv = xp[(size_t)t * (CC / 2)];
        float nr0 = fmaf(hr0, a_r.x, fmaf(-hi0, a_i.x, xv.x));
        float ni0 = fmaf(a_i.x, hr0, a_r.x * hi0);
        float nr1 = fmaf(hr1, a_r.y, fmaf(-hi1, a_i.y, xv.y));
        float ni1 = fmaf(a_i.y, hr1, a_r.y * hi1);
        hr0 = nr0; hi0 = ni0; hr1 = nr1; hi1 = ni1;
        op[(size_t)t * (CC / 2)] = make_float4(nr0, ni0, nr1, ni1);
    }
}

extern "C" void kernel_launch(void* const* d_in, const int* in_sizes, int n_in,
                              void* d_out, int out_size, void* d_ws, size_t ws_size,
                              hipStream_t stream) {
    const float* x   = (const float*)d_in[0];
    const float* Ar  = (const float*)d_in[1];
    const float* Ai  = (const float*)d_in[2];
    const float* h0r = (const float*)d_in[3];
    const float* h0i = (const float*)d_in[4];
    float* out = (float*)d_out;

    // workspace: s_end and h_start, each NCHUNK*BB*CC float2 (4 MiB each)
    float2* s_end   = (float2*)d_ws;
    float2* h_start = s_end + (size_t)NCHUNK * BB * CC;

    rec_pass1<<<BB * NCHUNK, 256, 0, stream>>>(x, Ar, Ai, s_end);
    rec_pass2<<<(BB * CC) / 256, 256, 0, stream>>>(Ar, Ai, h0r, h0i, s_end, h_start);
    rec_pass3<<<BB * NCHUNK, 256, 0, stream>>>(x, Ar, Ai, h_start, (float4*)out);
}

// Round 2
// 207.018 us; speedup vs baseline: 1.0230x; 1.0230x over previous
//
#include <hip/hip_runtime.h>

#define BB 8
#define TT 4096
#define CC 512
#define NCHUNK 128
#define LCHUNK (TT / NCHUNK)   // 32

// Kernel 1: per-chunk local scan with zero initial state; store chunk-end
// state as float4 (2 channels' r,i interleaved), layout [chunk][b][c/2].
__global__ __launch_bounds__(256, 4) void rec_ends(const float* __restrict__ x,
                                                   const float* __restrict__ Ar,
                                                   const float* __restrict__ Ai,
                                                   float4* __restrict__ s_end) {
    const int tid   = threadIdx.x;            // channels 2*tid, 2*tid+1
    const int blk   = blockIdx.x;
    const int b     = blk / NCHUNK;
    const int chunk = blk % NCHUNK;
    const int t0    = chunk * LCHUNK;

    const float2 a_r = ((const float2*)Ar)[tid];
    const float2 a_i = ((const float2*)Ai)[tid];

    const float2* xp = (const float2*)(x + (size_t)(b * TT + t0) * CC) + tid;

    float hr0 = 0.f, hi0 = 0.f, hr1 = 0.f, hi1 = 0.f;
#pragma unroll 8
    for (int t = 0; t < LCHUNK; ++t) {
        float2 xv = xp[(size_t)t * (CC / 2)];
        float nr0 = fmaf(hr0, a_r.x, fmaf(-hi0, a_i.x, xv.x));
        float ni0 = fmaf(a_i.x, hr0, a_r.x * hi0);
        float nr1 = fmaf(hr1, a_r.y, fmaf(-hi1, a_i.y, xv.y));
        float ni1 = fmaf(a_i.y, hr1, a_r.y * hi1);
        hr0 = nr0; hi0 = ni0; hr1 = nr1; hi1 = ni1;
    }
    s_end[(size_t)(chunk * BB + b) * (CC / 2) + tid] = make_float4(hr0, hi0, hr1, hi1);
}

// Kernel 2: each block computes its own chunk-start state (prefix over
// earlier chunks' end-states via A^L), then re-runs its 32 steps and emits.
__global__ __launch_bounds__(256, 4) void rec_emit(const float* __restrict__ x,
                                                   const float* __restrict__ Ar,
                                                   const float* __restrict__ Ai,
                                                   const float* __restrict__ h0r,
                                                   const float* __restrict__ h0i,
                                                   const float4* __restrict__ s_end,
                                                   float4* __restrict__ out) {
    const int tid   = threadIdx.x;
    const int blk   = blockIdx.x;
    const int b     = blk / NCHUNK;
    const int chunk = blk % NCHUNK;
    const int t0    = chunk * LCHUNK;

    const float2 a_r = ((const float2*)Ar)[tid];
    const float2 a_i = ((const float2*)Ai)[tid];

    // A^LCHUNK per channel (LCHUNK = 32 = 2^5 -> 5 complex squarings)
    float p0r = a_r.x, p0i = a_i.x, p1r = a_r.y, p1i = a_i.y;
#pragma unroll
    for (int s = 0; s < 5; ++s) {
        float n0r = p0r * p0r - p0i * p0i, n0i = 2.f * p0r * p0i;
        float n1r = p1r * p1r - p1i * p1i, n1i = 2.f * p1r * p1i;
        p0r = n0r; p0i = n0i; p1r = n1r; p1i = n1i;
    }

    // chunk-start state: h = h0; for j<chunk: h = A^L*h + s_end[j]
    float2 h0rv = ((const float2*)(h0r + (size_t)b * CC))[tid];
    float2 h0iv = ((const float2*)(h0i + (size_t)b * CC))[tid];
    float hr0 = h0rv.x, hr1 = h0rv.y, hi0 = h0iv.x, hi1 = h0iv.y;

    const float4* sp = s_end + tid;
#pragma unroll 4
    for (int j = 0; j < chunk; ++j) {
        float4 s = sp[(size_t)(j * BB + b) * (CC / 2)];
        float nr0 = p0r * hr0 - p0i * hi0 + s.x;
        float ni0 = p0i * hr0 + p0r * hi0 + s.y;
        float nr1 = p1r * hr1 - p1i * hi1 + s.z;
        float ni1 = p1i * hr1 + p1r * hi1 + s.w;
        hr0 = nr0; hi0 = ni0; hr1 = nr1; hi1 = ni1;
    }

    // emit 32 steps
    const float2* xp = (const float2*)(x + (size_t)(b * TT + t0) * CC) + tid;
    float4* op = out + (size_t)(b * TT + t0) * (CC / 2) + tid;
#pragma unroll 8
    for (int t = 0; t < LCHUNK; ++t) {
        float2 xv = xp[(size_t)t * (CC / 2)];
        float nr0 = fmaf(hr0, a_r.x, fmaf(-hi0, a_i.x, xv.x));
        float ni0 = fmaf(a_i.x, hr0, a_r.x * hi0);
        float nr1 = fmaf(hr1, a_r.y, fmaf(-hi1, a_i.y, xv.y));
        float ni1 = fmaf(a_i.y, hr1, a_r.y * hi1);
        hr0 = nr0; hi0 = ni0; hr1 = nr1; hi1 = ni1;
        op[(size_t)t * (CC / 2)] = make_float4(nr0, ni0, nr1, ni1);
    }
}

extern "C" void kernel_launch(void* const* d_in, const int* in_sizes, int n_in,
                              void* d_out, int out_size, void* d_ws, size_t ws_size,
                              hipStream_t stream) {
    const float* x   = (const float*)d_in[0];
    const float* Ar  = (const float*)d_in[1];
    const float* Ai  = (const float*)d_in[2];
    const float* h0r = (const float*)d_in[3];
    const float* h0i = (const float*)d_in[4];
    float* out = (float*)d_out;

    float4* s_end = (float4*)d_ws;   // NCHUNK*BB*(CC/2) float4 = 4 MiB

    rec_ends<<<BB * NCHUNK, 256, 0, stream>>>(x, Ar, Ai, s_end);
    rec_emit<<<BB * NCHUNK, 256, 0, stream>>>(x, Ar, Ai, h0r, h0i, s_end, (float4*)out);
}